// Round 6
// baseline (373.888 us; speedup 1.0000x reference)
//
#include <hip/hip_runtime.h>
#include <hip/hip_bf16.h>

// SlotAttention on MI355X. B=64, N=4096, Din=D=64, S=7, H=128, 3 iters.
// v6: no cooperative launch. 5 launches: prep, proj(+slots-init+q), 3x attn_post.
// attn_post fuses the per-batch GRU/LN/MLP/next-q via a fence+counter: the
// 16th-arriving block of each batch runs the post phase for that batch.
// proj/attn bodies are the round-4 HW-verified versions (absmax 0.0156).

#define NB 64
#define NN 4096
#define NS 7
#define LN_EPS 1e-3f
#define EPS_ATTN 1e-8f

typedef __attribute__((ext_vector_type(8))) __bf16 bf16x8;
typedef __attribute__((ext_vector_type(8))) unsigned short u16x8;
typedef __attribute__((ext_vector_type(4))) float f32x4;
typedef __attribute__((ext_vector_type(4))) unsigned int u32x4;

__device__ __forceinline__ unsigned short f2bf(float f) {
    unsigned int x = __float_as_uint(f);
    x += 0x7FFFu + ((x >> 16) & 1u);
    return (unsigned short)(x >> 16);
}

__device__ __forceinline__ bf16x8 pack8(float4 a, float4 b) {
    u16x8 r;
    r[0] = f2bf(a.x); r[1] = f2bf(a.y); r[2] = f2bf(a.z); r[3] = f2bf(a.w);
    r[4] = f2bf(b.x); r[5] = f2bf(b.y); r[6] = f2bf(b.z); r[7] = f2bf(b.w);
    return __builtin_bit_cast(bf16x8, r);
}

// ---------------- prep: G^T = (g (.) W)^T bf16, colsums ----------------
__global__ __launch_bounds__(64) void prep_kernel(
        const float* __restrict__ Wk, const float* __restrict__ Wv,
        const float* __restrict__ g, const float* __restrict__ bb,
        unsigned short* __restrict__ GkT, unsigned short* __restrict__ GvT,
        float* __restrict__ cgk, float* __restrict__ cbk,
        float* __restrict__ cgv, float* __restrict__ cbv) {
    int j = blockIdx.x & 63, mat = blockIdx.x >> 6, d = threadIdx.x;
    const float* W = mat ? Wv : Wk;
    unsigned short* GT = mat ? GvT : GkT;
    float* cg = mat ? cgv : cgk;
    float* cb = mat ? cbv : cbk;
    float w = W[d * 64 + j];
    float gv = g[d], bv = bb[d];
    GT[j * 64 + d] = f2bf(gv * w);
    float sg = gv * w, sb = bv * w;
#pragma unroll
    for (int off = 1; off < 64; off <<= 1) {
        sg += __shfl_xor(sg, off);
        sb += __shfl_xor(sb, off);
    }
    if (d == 0) { cg[j] = sg; cb[j] = sb; }
}

// ---------------- proj (+ slots init + q + zero U/Z/cnt in blocks 0..447) ----------------
__global__ __launch_bounds__(256) void proj_kernel(
        const float* __restrict__ x, const unsigned short* __restrict__ GkT,
        const unsigned short* __restrict__ GvT,
        const float* __restrict__ cgk, const float* __restrict__ cbk,
        const float* __restrict__ cgv, const float* __restrict__ cbv,
        unsigned short* __restrict__ kout, unsigned short* __restrict__ vT,
        const float* __restrict__ noise, const float* __restrict__ mu,
        const float* __restrict__ lsig,
        const float* __restrict__ Wq, const float* __restrict__ lsg,
        const float* __restrict__ lsb,
        float* __restrict__ slots, float* __restrict__ q,
        float* __restrict__ U, float* __restrict__ Z, int* __restrict__ cnt) {
    __shared__ __align__(16) unsigned short ktile[128 * 72];   // [row][72]
    __shared__ __align__(16) unsigned short vtile[64 * 136];   // [d][136]
    int t = threadIdx.x;
    int w = t >> 6, lane = t & 63;
    int h = lane >> 4, rl = lane & 15;
    long base = (long)blockIdx.x * 128;         // block = 128 rows
    int bb = blockIdx.x >> 5;                   // batch
    int nblk = (blockIdx.x & 31) * 128;         // n offset within batch
    const float* xr0 = x + (base + w * 16 + rl) * 64 + h * 8;
    const float* xr1 = xr0 + 64 * 64;
    float4 xa[8];
    xa[0] = *(const float4*)(xr0);      xa[1] = *(const float4*)(xr0 + 4);
    xa[2] = *(const float4*)(xr0 + 32); xa[3] = *(const float4*)(xr0 + 36);
    xa[4] = *(const float4*)(xr1);      xa[5] = *(const float4*)(xr1 + 4);
    xa[6] = *(const float4*)(xr1 + 32); xa[7] = *(const float4*)(xr1 + 36);
    float s1a = 0.f, s2a = 0.f, s1b = 0.f, s2b = 0.f;
#pragma unroll
    for (int i = 0; i < 4; ++i) {
        s1a += xa[i].x + xa[i].y + xa[i].z + xa[i].w;
        s2a += xa[i].x * xa[i].x + xa[i].y * xa[i].y + xa[i].z * xa[i].z + xa[i].w * xa[i].w;
        s1b += xa[4 + i].x + xa[4 + i].y + xa[4 + i].z + xa[4 + i].w;
        s2b += xa[4 + i].x * xa[4 + i].x + xa[4 + i].y * xa[4 + i].y
             + xa[4 + i].z * xa[4 + i].z + xa[4 + i].w * xa[4 + i].w;
    }
    s1a += __shfl_xor(s1a, 16); s2a += __shfl_xor(s2a, 16);
    s1a += __shfl_xor(s1a, 32); s2a += __shfl_xor(s2a, 32);
    s1b += __shfl_xor(s1b, 16); s2b += __shfl_xor(s2b, 16);
    s1b += __shfl_xor(s1b, 32); s2b += __shfl_xor(s2b, 32);
    float m0 = s1a * (1.f / 64.f);
    float i0 = rsqrtf(s2a * (1.f / 64.f) - m0 * m0 + LN_EPS);
    float m1 = s1b * (1.f / 64.f);
    float i1 = rsqrtf(s2b * (1.f / 64.f) - m1 * m1 + LN_EPS);
    bf16x8 a00 = pack8(xa[0], xa[1]), a01 = pack8(xa[2], xa[3]);
    bf16x8 a10 = pack8(xa[4], xa[5]), a11 = pack8(xa[6], xa[7]);
    f32x4 k0a[4], v0a[4], k1a[4], v1a[4];
#pragma unroll
    for (int nt = 0; nt < 4; ++nt) {
        k0a[nt] = (f32x4){0.f, 0.f, 0.f, 0.f}; v0a[nt] = (f32x4){0.f, 0.f, 0.f, 0.f};
        k1a[nt] = (f32x4){0.f, 0.f, 0.f, 0.f}; v1a[nt] = (f32x4){0.f, 0.f, 0.f, 0.f};
    }
#pragma unroll
    for (int nt = 0; nt < 4; ++nt) {
        const unsigned short* gk = GkT + (nt * 16 + rl) * 64 + h * 8;
        const unsigned short* gv = GvT + (nt * 16 + rl) * 64 + h * 8;
        bf16x8 bk0 = *(const bf16x8*)(gk);
        bf16x8 bk1 = *(const bf16x8*)(gk + 32);
        bf16x8 bv0 = *(const bf16x8*)(gv);
        bf16x8 bv1 = *(const bf16x8*)(gv + 32);
        k0a[nt] = __builtin_amdgcn_mfma_f32_16x16x32_bf16(a00, bk0, k0a[nt], 0, 0, 0);
        k0a[nt] = __builtin_amdgcn_mfma_f32_16x16x32_bf16(a01, bk1, k0a[nt], 0, 0, 0);
        v0a[nt] = __builtin_amdgcn_mfma_f32_16x16x32_bf16(a00, bv0, v0a[nt], 0, 0, 0);
        v0a[nt] = __builtin_amdgcn_mfma_f32_16x16x32_bf16(a01, bv1, v0a[nt], 0, 0, 0);
        k1a[nt] = __builtin_amdgcn_mfma_f32_16x16x32_bf16(a10, bk0, k1a[nt], 0, 0, 0);
        k1a[nt] = __builtin_amdgcn_mfma_f32_16x16x32_bf16(a11, bk1, k1a[nt], 0, 0, 0);
        v1a[nt] = __builtin_amdgcn_mfma_f32_16x16x32_bf16(a10, bv0, v1a[nt], 0, 0, 0);
        v1a[nt] = __builtin_amdgcn_mfma_f32_16x16x32_bf16(a11, bv1, v1a[nt], 0, 0, 0);
    }
    float mr0[4], ir0[4], mr1[4], ir1[4];
#pragma unroll
    for (int r = 0; r < 4; ++r) {
        int rlsrc = h * 4 + r;
        mr0[r] = __shfl(m0, rlsrc); ir0[r] = __shfl(i0, rlsrc);
        mr1[r] = __shfl(m1, rlsrc); ir1[r] = __shfl(i1, rlsrc);
    }
#pragma unroll
    for (int nt = 0; nt < 4; ++nt) {
        int j = nt * 16 + rl;
        float cgkj = cgk[j], cbkj = cbk[j], cgvj = cgv[j], cbvj = cbv[j];
        unsigned short vv0[4], vv1[4];
#pragma unroll
        for (int r = 0; r < 4; ++r) {
            int row = w * 16 + h * 4 + r;
            ktile[row * 72 + j] = f2bf(ir0[r] * (k0a[nt][r] - mr0[r] * cgkj) + cbkj);
            ktile[(64 + row) * 72 + j] = f2bf(ir1[r] * (k1a[nt][r] - mr1[r] * cgkj) + cbkj);
            vv0[r] = f2bf(ir0[r] * (v0a[nt][r] - mr0[r] * cgvj) + cbvj);
            vv1[r] = f2bf(ir1[r] * (v1a[nt][r] - mr1[r] * cgvj) + cbvj);
        }
        uint2 p0 = make_uint2((unsigned int)vv0[0] | ((unsigned int)vv0[1] << 16),
                              (unsigned int)vv0[2] | ((unsigned int)vv0[3] << 16));
        uint2 p1 = make_uint2((unsigned int)vv1[0] | ((unsigned int)vv1[1] << 16),
                              (unsigned int)vv1[2] | ((unsigned int)vv1[3] << 16));
        *(uint2*)(&vtile[j * 136 + w * 16 + h * 4]) = p0;
        *(uint2*)(&vtile[j * 136 + 64 + w * 16 + h * 4]) = p1;
    }
    __syncthreads();
#pragma unroll
    for (int i = 0; i < 4; ++i) {
        int flat = (i * 256 + t) * 8;
        int row = flat >> 6, col = flat & 63;
        uint4 kd = *(const uint4*)(&ktile[row * 72 + col]);
        *(uint4*)(kout + (base + row) * 64 + col) = kd;
        int dd = flat >> 7, noff = flat & 127;
        uint4 vd = *(const uint4*)(&vtile[dd * 136 + noff]);
        *(uint4*)(vT + ((long)(bb * 64 + dd)) * NN + nblk + noff) = vd;
    }
    // ---- tail: slots init + LN_s + q + zero U/Z/cnt (blocks 0..447) ----
    if (blockIdx.x < 448) {
        int bs = blockIdx.x;
        __syncthreads();
        float* sn = (float*)ktile;
        if (t < 64) {
            float xv = mu[t] + __expf(lsig[t]) * noise[bs * 64 + t];
            slots[bs * 64 + t] = xv;
            float s1 = xv, s2 = xv * xv;
#pragma unroll
            for (int off = 1; off < 64; off <<= 1) {
                s1 += __shfl_xor(s1, off);
                s2 += __shfl_xor(s2, off);
            }
            float m = s1 * (1.f / 64.f);
            float inv = rsqrtf(s2 * (1.f / 64.f) - m * m + LN_EPS);
            sn[t] = (xv - m) * inv * lsg[t] + lsb[t];
            U[bs * 64 + t] = 0.f;
            if (t == 0) Z[bs] = 0.f;
            if (bs < 64 && t == 0) cnt[bs] = 0;
        }
        __syncthreads();
        if (t < 64) {
            float acc = 0.f;
#pragma unroll 8
            for (int i = 0; i < 64; ++i) acc += sn[i] * Wq[i * 64 + t];
            q[bs * 64 + t] = acc * 0.125f;
        }
    }
}

// ---------------- attn + fused last-block post ----------------
__global__ __launch_bounds__(256) void attn_post_kernel(
        const unsigned short* __restrict__ kp, const unsigned short* __restrict__ vtp,
        float* __restrict__ q, float* __restrict__ U, float* __restrict__ Z,
        int* __restrict__ cnt, float* __restrict__ slots,
        const float* __restrict__ gW, const float* __restrict__ gU,
        const float* __restrict__ gb,
        const float* __restrict__ lmg, const float* __restrict__ lmb,
        const float* __restrict__ W1, const float* __restrict__ b1,
        const float* __restrict__ W2, const float* __restrict__ b2,
        const float* __restrict__ Wq, const float* __restrict__ lsg,
        const float* __restrict__ lsb,
        float* __restrict__ outp, int last) {
    __shared__ __align__(16) char smemraw[38912];
    __shared__ int islast;
    unsigned short* vtile = (unsigned short*)smemraw;          // [64][264] bf16
    unsigned int* plds = (unsigned int*)(smemraw + 33792);     // [4][320]
    int t = threadIdx.x;
    int b = blockIdx.x >> 4, blk = blockIdx.x & 15;
    int w = t >> 6, lane = t & 63;
    int h = lane >> 4, c = lane & 15;
    // stage vT tile: 64 d x 256 n, coalesced 512B row segments
#pragma unroll
    for (int i = 0; i < 8; ++i) {
        int flat = (i * 256 + t) * 8;
        int dd = flat >> 8, noff = flat & 255;
        uint4 vv = *(const uint4*)(vtp + ((long)(b * 64 + dd)) * NN + blk * 256 + noff);
        *(uint4*)(&vtile[dd * 264 + noff]) = vv;
    }
    // q B-fragments (slot = c; zero for c >= 7)
    bf16x8 qf0, qf1;
    {
        int cs = (c < 7) ? c : 0;
        const float* qr = q + (b * NS + cs) * 64 + h * 8;
        float4 q0 = *(const float4*)(qr);
        float4 q1 = *(const float4*)(qr + 4);
        float4 q2 = *(const float4*)(qr + 32);
        float4 q3 = *(const float4*)(qr + 36);
        if (c >= 7) {
            q0 = make_float4(0.f, 0.f, 0.f, 0.f); q1 = q0; q2 = q0; q3 = q0;
        }
        qf0 = pack8(q0, q1);
        qf1 = pack8(q2, q3);
    }
    f32x4 pv[4];
#pragma unroll
    for (int i = 0; i < 4; ++i) pv[i] = (f32x4){0.f, 0.f, 0.f, 0.f};
    float zac = 0.f;
    unsigned int* pw = plds + w * 320;
    long rb0 = (long)b * NN + blk * 256 + w * 16;
    __syncthreads();
#pragma unroll
    for (int p = 0; p < 2; ++p) {
#pragma unroll
        for (int sh = 0; sh < 2; ++sh) {
            long rowbase = rb0 + p * 128 + sh * 64;
            const unsigned short* ka = kp + (rowbase + c) * 64 + h * 8;
            bf16x8 a0 = *(const bf16x8*)(ka);
            bf16x8 a1 = *(const bf16x8*)(ka + 32);
            f32x4 lg = (f32x4){0.f, 0.f, 0.f, 0.f};
            lg = __builtin_amdgcn_mfma_f32_16x16x32_bf16(a0, qf0, lg, 0, 0, 0);
            lg = __builtin_amdgcn_mfma_f32_16x16x32_bf16(a1, qf1, lg, 0, 0, 0);
            float av[4];
#pragma unroll
            for (int j = 0; j < 4; ++j) {
                float vl = (c < 7) ? lg[j] : -1e30f;
                float mx = vl;
                mx = fmaxf(mx, __shfl_xor(mx, 1));
                mx = fmaxf(mx, __shfl_xor(mx, 2));
                mx = fmaxf(mx, __shfl_xor(mx, 4));
                mx = fmaxf(mx, __shfl_xor(mx, 8));
                float e = (c < 7) ? __expf(lg[j] - mx) : 0.f;
                float se = e;
                se += __shfl_xor(se, 1);
                se += __shfl_xor(se, 2);
                se += __shfl_xor(se, 4);
                se += __shfl_xor(se, 8);
                float a = (c < 7) ? (__fdividef(e, se) + EPS_ATTN) : 0.f;
                av[j] = a;
                zac += a;
            }
            unsigned int w0 = (unsigned int)f2bf(av[0]) | ((unsigned int)f2bf(av[1]) << 16);
            unsigned int w1 = (unsigned int)f2bf(av[2]) | ((unsigned int)f2bf(av[3]) << 16);
            pw[c * 20 + sh * 8 + 2 * h]     = w0;
            pw[c * 20 + sh * 8 + 2 * h + 1] = w1;
        }
        // PV: A = P^T (rows=slots), B = V from LDS vT tile
        u32x4 pr = *(u32x4*)(&pw[c * 20 + 4 * h]);
        bf16x8 pa = __builtin_bit_cast(bf16x8, pr);
        int nloc = p * 128 + ((h < 2) ? (w * 16 + 8 * h) : (48 + w * 16 + 8 * h));
#pragma unroll
        for (int tile = 0; tile < 4; ++tile) {
            bf16x8 bv = *(const bf16x8*)(&vtile[(tile * 16 + c) * 264 + nloc]);
            pv[tile] = __builtin_amdgcn_mfma_f32_16x16x32_bf16(pa, bv, pv[tile], 0, 0, 0);
        }
    }
    // Z reduce
    zac += __shfl_xor(zac, 16);
    zac += __shfl_xor(zac, 32);
    if (h == 0 && c < 7) atomicAdd(Z + b * NS + c, zac);
    __syncthreads();   // before aliasing vtile as ured
    float* ured = (float*)smemraw;   // [4][512]
    if (h < 2) {
#pragma unroll
        for (int tile = 0; tile < 4; ++tile) {
#pragma unroll
            for (int j = 0; j < 4; ++j) {
                ured[w * 512 + (4 * h + j) * 64 + tile * 16 + c] = pv[tile][j];
            }
        }
    }
    __syncthreads();
    for (int idx = t; idx < NS * 64; idx += 256) {
        float tot = ured[idx] + ured[512 + idx] + ured[1024 + idx] + ured[1536 + idx];
        atomicAdd(&U[b * (NS * 64) + idx], tot);
    }
    // ---- arrival counter: 16th block of batch b runs the post phase ----
    __syncthreads();   // drains each wave's vmcnt -> all U/Z atomics complete
    if (t == 0) {
        __threadfence();
        int old = atomicAdd(&cnt[b], 1);
        islast = (old == 15) ? 1 : 0;
    }
    __syncthreads();
    if (!islast) return;
    __threadfence();
    // ---- post for batch b (7 slots, slot-vectorized) ----
    float* S   = (float*)smemraw;
    float* up  = S;            // 448
    float* hp  = S + 448;      // 448
    float* hn  = S + 896;      // 448
    float* mxs = S + 1344;     // 7*192
    float* mhs = S + 2688;     // 7*192
    float* mm  = S + 4032;     // 448
    float* hl  = S + 4480;     // 7*128
    float* sl  = S + 5376;     // 448
    float* snv = S + 5824;     // 448
    float* zs  = S + 6272;     // 7
    if (t < NS)
        zs[t] = __hip_atomic_load(&Z[b * NS + t], __ATOMIC_RELAXED, __HIP_MEMORY_SCOPE_AGENT);
    for (int idx = t; idx < 448; idx += 256) {
        up[idx] = __hip_atomic_load(&U[b * 448 + idx], __ATOMIC_RELAXED, __HIP_MEMORY_SCOPE_AGENT);
        hp[idx] = slots[b * 448 + idx];
    }
    __syncthreads();
    for (int idx = t; idx < 448; idx += 256) {
        up[idx] /= zs[idx >> 6];
        U[b * 448 + idx] = 0.f;
    }
    if (t < NS) Z[b * NS + t] = 0.f;
    if (t == 0) cnt[b] = 0;
    __syncthreads();
    if (t < 192) {
        float ax[7], ah[7];
#pragma unroll
        for (int s = 0; s < 7; ++s) { ax[s] = gb[t]; ah[s] = gb[192 + t]; }
        for (int i = 0; i < 64; ++i) {
            float wx = gW[i * 192 + t], wh = gU[i * 192 + t];
#pragma unroll
            for (int s = 0; s < 7; ++s) {
                ax[s] += up[s * 64 + i] * wx;
                ah[s] += hp[s * 64 + i] * wh;
            }
        }
#pragma unroll
        for (int s = 0; s < 7; ++s) { mxs[s * 192 + t] = ax[s]; mhs[s * 192 + t] = ah[s]; }
    }
    __syncthreads();
#pragma unroll
    for (int pass = 0; pass < 2; ++pass) {
        int idx = pass * 256 + t;
        if (idx < 448) {
            int s = idx >> 6, d = idx & 63;
            float z = 1.f / (1.f + __expf(-(mxs[s * 192 + d] + mhs[s * 192 + d])));
            float r = 1.f / (1.f + __expf(-(mxs[s * 192 + 64 + d] + mhs[s * 192 + 64 + d])));
            float pre = mxs[s * 192 + 128 + d] + r * mhs[s * 192 + 128 + d];
            pre = fminf(fmaxf(pre, -15.f), 15.f);
            float e2 = __expf(2.f * pre);
            float hc = (e2 - 1.f) / (e2 + 1.f);
            float hnew = z * hp[idx] + (1.f - z) * hc;
            hn[idx] = hnew;
            float s1 = hnew, s2 = hnew * hnew;
#pragma unroll
            for (int off = 1; off < 64; off <<= 1) {
                s1 += __shfl_xor(s1, off); s2 += __shfl_xor(s2, off);
            }
            float m = s1 * (1.f / 64.f);
            float inv = rsqrtf(s2 * (1.f / 64.f) - m * m + LN_EPS);
            mm[idx] = (hnew - m) * inv * lmg[d] + lmb[d];
        }
    }
    __syncthreads();
    if (t < 128) {
        float acc[7];
#pragma unroll
        for (int s = 0; s < 7; ++s) acc[s] = b1[t];
        for (int i = 0; i < 64; ++i) {
            float wv = W1[i * 128 + t];
#pragma unroll
            for (int s = 0; s < 7; ++s) acc[s] += mm[s * 64 + i] * wv;
        }
#pragma unroll
        for (int s = 0; s < 7; ++s) hl[s * 128 + t] = fmaxf(acc[s], 0.f);
    }
    __syncthreads();
    if (t < 64) {
        float o[7];
#pragma unroll
        for (int s = 0; s < 7; ++s) o[s] = hn[s * 64 + t] + b2[t];
        for (int j = 0; j < 128; ++j) {
            float wv = W2[j * 64 + t];
#pragma unroll
            for (int s = 0; s < 7; ++s) o[s] += hl[s * 128 + j] * wv;
        }
#pragma unroll
        for (int s = 0; s < 7; ++s) {
            sl[s * 64 + t] = o[s];
            slots[b * 448 + s * 64 + t] = o[s];
            if (last) outp[b * 448 + s * 64 + t] = o[s];
        }
    }
    __syncthreads();
#pragma unroll
    for (int pass = 0; pass < 2; ++pass) {
        int idx = pass * 256 + t;
        if (idx < 448) {
            int d = idx & 63;
            float o = sl[idx];
            float s1 = o, s2 = o * o;
#pragma unroll
            for (int off = 1; off < 64; off <<= 1) {
                s1 += __shfl_xor(s1, off); s2 += __shfl_xor(s2, off);
            }
            float m = s1 * (1.f / 64.f);
            float inv = rsqrtf(s2 * (1.f / 64.f) - m * m + LN_EPS);
            snv[idx] = (o - m) * inv * lsg[d] + lsb[d];
        }
    }
    __syncthreads();
#pragma unroll
    for (int pass = 0; pass < 2; ++pass) {
        int idx = pass * 256 + t;
        if (idx < 448) {
            int s = idx >> 6, d = idx & 63;
            float acc = 0.f;
#pragma unroll 8
            for (int i = 0; i < 64; ++i) acc += snv[s * 64 + i] * Wq[i * 64 + d];
            q[b * 448 + idx] = acc * 0.125f;
        }
    }
}

extern "C" void kernel_launch(void* const* d_in, const int* in_sizes, int n_in,
                              void* d_out, int out_size, void* d_ws, size_t ws_size,
                              hipStream_t stream) {
    const float* inputs  = (const float*)d_in[0];
    const float* noise   = (const float*)d_in[1];
    const float* ln_in_g = (const float*)d_in[2];
    const float* ln_in_b = (const float*)d_in[3];
    const float* ln_s_g  = (const float*)d_in[4];
    const float* ln_s_b  = (const float*)d_in[5];
    const float* ln_m_g  = (const float*)d_in[6];
    const float* ln_m_b  = (const float*)d_in[7];
    const float* Wq      = (const float*)d_in[8];
    const float* Wk      = (const float*)d_in[9];
    const float* Wv      = (const float*)d_in[10];
    const float* mu      = (const float*)d_in[11];
    const float* lsig    = (const float*)d_in[12];
    const float* gW      = (const float*)d_in[13];
    const float* gU      = (const float*)d_in[14];
    const float* gb      = (const float*)d_in[15];
    const float* W1      = (const float*)d_in[16];
    const float* b1      = (const float*)d_in[17];
    const float* W2      = (const float*)d_in[18];
    const float* b2      = (const float*)d_in[19];

    char* ws = (char*)d_ws;
    unsigned short* kbuf  = (unsigned short*)ws;                       // 32MB, [b*4096+n][64]
    unsigned short* vtbuf = (unsigned short*)(ws + 33554432);          // 32MB, [b][64][4096]
    float* slots = (float*)(ws + 67108864);
    float* qbuf  = (float*)(ws + 67108864 + 114688);
    float* Ubuf  = (float*)(ws + 67108864 + 2 * 114688);
    float* Zbuf  = (float*)(ws + 67108864 + 3 * 114688);
    unsigned short* GkT = (unsigned short*)(ws + 67108864 + 3 * 114688 + 4096);
    unsigned short* GvT = GkT + 4096;
    float* cgk = (float*)(GvT + 4096);
    float* cbk = cgk + 64;
    float* cgv = cbk + 64;
    float* cbv = cgv + 64;
    int*   cnt = (int*)(cbv + 64);
    float* outp = (float*)d_out;

    prep_kernel<<<128, 64, 0, stream>>>(Wk, Wv, ln_in_g, ln_in_b, GkT, GvT, cgk, cbk, cgv, cbv);
    proj_kernel<<<2048, 256, 0, stream>>>(inputs, GkT, GvT, cgk, cbk, cgv, cbv, kbuf, vtbuf,
                                          noise, mu, lsig, Wq, ln_s_g, ln_s_b,
                                          slots, qbuf, Ubuf, Zbuf, cnt);
    for (int it = 0; it < 3; ++it) {
        attn_post_kernel<<<1024, 256, 0, stream>>>(kbuf, vtbuf, qbuf, Ubuf, Zbuf, cnt, slots,
                                                   gW, gU, gb, ln_m_g, ln_m_b,
                                                   W1, b1, W2, b2, Wq, ln_s_g, ln_s_b,
                                                   outp, (it == 2) ? 1 : 0);
    }
}

// Round 7
// 253.149 us; speedup vs baseline: 1.4770x; 1.4770x over previous
//
#include <hip/hip_runtime.h>
#include <hip/hip_bf16.h>

// SlotAttention on MI355X. B=64, N=4096, Din=D=64, S=7, H=128, 3 iters.
// v7: revert v6's fence fusion (measured -120us). Split kernels:
// prep, proj(+slots-init+q tail), 3x (attn, post). attn = round-4 verified
// body with ALL loads (k-frags + vT staging + q) hoisted into one volley
// before a single barrier -> one latency exposure instead of four.

#define NB 64
#define NN 4096
#define NS 7
#define LN_EPS 1e-3f
#define EPS_ATTN 1e-8f

typedef __attribute__((ext_vector_type(8))) __bf16 bf16x8;
typedef __attribute__((ext_vector_type(8))) unsigned short u16x8;
typedef __attribute__((ext_vector_type(4))) float f32x4;
typedef __attribute__((ext_vector_type(4))) unsigned int u32x4;

__device__ __forceinline__ unsigned short f2bf(float f) {
    unsigned int x = __float_as_uint(f);
    x += 0x7FFFu + ((x >> 16) & 1u);
    return (unsigned short)(x >> 16);
}

__device__ __forceinline__ bf16x8 pack8(float4 a, float4 b) {
    u16x8 r;
    r[0] = f2bf(a.x); r[1] = f2bf(a.y); r[2] = f2bf(a.z); r[3] = f2bf(a.w);
    r[4] = f2bf(b.x); r[5] = f2bf(b.y); r[6] = f2bf(b.z); r[7] = f2bf(b.w);
    return __builtin_bit_cast(bf16x8, r);
}

// ---------------- prep: G^T = (g (.) W)^T bf16, colsums ----------------
__global__ __launch_bounds__(64) void prep_kernel(
        const float* __restrict__ Wk, const float* __restrict__ Wv,
        const float* __restrict__ g, const float* __restrict__ bb,
        unsigned short* __restrict__ GkT, unsigned short* __restrict__ GvT,
        float* __restrict__ cgk, float* __restrict__ cbk,
        float* __restrict__ cgv, float* __restrict__ cbv) {
    int j = blockIdx.x & 63, mat = blockIdx.x >> 6, d = threadIdx.x;
    const float* W = mat ? Wv : Wk;
    unsigned short* GT = mat ? GvT : GkT;
    float* cg = mat ? cgv : cgk;
    float* cb = mat ? cbv : cbk;
    float w = W[d * 64 + j];
    float gv = g[d], bv = bb[d];
    GT[j * 64 + d] = f2bf(gv * w);
    float sg = gv * w, sb = bv * w;
#pragma unroll
    for (int off = 1; off < 64; off <<= 1) {
        sg += __shfl_xor(sg, off);
        sb += __shfl_xor(sb, off);
    }
    if (d == 0) { cg[j] = sg; cb[j] = sb; }
}

// ---------------- proj (+ slots init + q + zero U/Z in blocks 0..447) ----------------
__global__ __launch_bounds__(256) void proj_kernel(
        const float* __restrict__ x, const unsigned short* __restrict__ GkT,
        const unsigned short* __restrict__ GvT,
        const float* __restrict__ cgk, const float* __restrict__ cbk,
        const float* __restrict__ cgv, const float* __restrict__ cbv,
        unsigned short* __restrict__ kout, unsigned short* __restrict__ vT,
        const float* __restrict__ noise, const float* __restrict__ mu,
        const float* __restrict__ lsig,
        const float* __restrict__ Wq, const float* __restrict__ lsg,
        const float* __restrict__ lsb,
        float* __restrict__ slots, float* __restrict__ q,
        float* __restrict__ U, float* __restrict__ Z) {
    __shared__ __align__(16) unsigned short ktile[128 * 72];   // [row][72]
    __shared__ __align__(16) unsigned short vtile[64 * 136];   // [d][136]
    int t = threadIdx.x;
    int w = t >> 6, lane = t & 63;
    int h = lane >> 4, rl = lane & 15;
    long base = (long)blockIdx.x * 128;         // block = 128 rows
    int bb = blockIdx.x >> 5;                   // batch
    int nblk = (blockIdx.x & 31) * 128;         // n offset within batch
    const float* xr0 = x + (base + w * 16 + rl) * 64 + h * 8;
    const float* xr1 = xr0 + 64 * 64;
    float4 xa[8];
    xa[0] = *(const float4*)(xr0);      xa[1] = *(const float4*)(xr0 + 4);
    xa[2] = *(const float4*)(xr0 + 32); xa[3] = *(const float4*)(xr0 + 36);
    xa[4] = *(const float4*)(xr1);      xa[5] = *(const float4*)(xr1 + 4);
    xa[6] = *(const float4*)(xr1 + 32); xa[7] = *(const float4*)(xr1 + 36);
    float s1a = 0.f, s2a = 0.f, s1b = 0.f, s2b = 0.f;
#pragma unroll
    for (int i = 0; i < 4; ++i) {
        s1a += xa[i].x + xa[i].y + xa[i].z + xa[i].w;
        s2a += xa[i].x * xa[i].x + xa[i].y * xa[i].y + xa[i].z * xa[i].z + xa[i].w * xa[i].w;
        s1b += xa[4 + i].x + xa[4 + i].y + xa[4 + i].z + xa[4 + i].w;
        s2b += xa[4 + i].x * xa[4 + i].x + xa[4 + i].y * xa[4 + i].y
             + xa[4 + i].z * xa[4 + i].z + xa[4 + i].w * xa[4 + i].w;
    }
    s1a += __shfl_xor(s1a, 16); s2a += __shfl_xor(s2a, 16);
    s1a += __shfl_xor(s1a, 32); s2a += __shfl_xor(s2a, 32);
    s1b += __shfl_xor(s1b, 16); s2b += __shfl_xor(s2b, 16);
    s1b += __shfl_xor(s1b, 32); s2b += __shfl_xor(s2b, 32);
    float m0 = s1a * (1.f / 64.f);
    float i0 = rsqrtf(s2a * (1.f / 64.f) - m0 * m0 + LN_EPS);
    float m1 = s1b * (1.f / 64.f);
    float i1 = rsqrtf(s2b * (1.f / 64.f) - m1 * m1 + LN_EPS);
    bf16x8 a00 = pack8(xa[0], xa[1]), a01 = pack8(xa[2], xa[3]);
    bf16x8 a10 = pack8(xa[4], xa[5]), a11 = pack8(xa[6], xa[7]);
    f32x4 k0a[4], v0a[4], k1a[4], v1a[4];
#pragma unroll
    for (int nt = 0; nt < 4; ++nt) {
        k0a[nt] = (f32x4){0.f, 0.f, 0.f, 0.f}; v0a[nt] = (f32x4){0.f, 0.f, 0.f, 0.f};
        k1a[nt] = (f32x4){0.f, 0.f, 0.f, 0.f}; v1a[nt] = (f32x4){0.f, 0.f, 0.f, 0.f};
    }
#pragma unroll
    for (int nt = 0; nt < 4; ++nt) {
        const unsigned short* gk = GkT + (nt * 16 + rl) * 64 + h * 8;
        const unsigned short* gv = GvT + (nt * 16 + rl) * 64 + h * 8;
        bf16x8 bk0 = *(const bf16x8*)(gk);
        bf16x8 bk1 = *(const bf16x8*)(gk + 32);
        bf16x8 bv0 = *(const bf16x8*)(gv);
        bf16x8 bv1 = *(const bf16x8*)(gv + 32);
        k0a[nt] = __builtin_amdgcn_mfma_f32_16x16x32_bf16(a00, bk0, k0a[nt], 0, 0, 0);
        k0a[nt] = __builtin_amdgcn_mfma_f32_16x16x32_bf16(a01, bk1, k0a[nt], 0, 0, 0);
        v0a[nt] = __builtin_amdgcn_mfma_f32_16x16x32_bf16(a00, bv0, v0a[nt], 0, 0, 0);
        v0a[nt] = __builtin_amdgcn_mfma_f32_16x16x32_bf16(a01, bv1, v0a[nt], 0, 0, 0);
        k1a[nt] = __builtin_amdgcn_mfma_f32_16x16x32_bf16(a10, bk0, k1a[nt], 0, 0, 0);
        k1a[nt] = __builtin_amdgcn_mfma_f32_16x16x32_bf16(a11, bk1, k1a[nt], 0, 0, 0);
        v1a[nt] = __builtin_amdgcn_mfma_f32_16x16x32_bf16(a10, bv0, v1a[nt], 0, 0, 0);
        v1a[nt] = __builtin_amdgcn_mfma_f32_16x16x32_bf16(a11, bv1, v1a[nt], 0, 0, 0);
    }
    float mr0[4], ir0[4], mr1[4], ir1[4];
#pragma unroll
    for (int r = 0; r < 4; ++r) {
        int rlsrc = h * 4 + r;
        mr0[r] = __shfl(m0, rlsrc); ir0[r] = __shfl(i0, rlsrc);
        mr1[r] = __shfl(m1, rlsrc); ir1[r] = __shfl(i1, rlsrc);
    }
#pragma unroll
    for (int nt = 0; nt < 4; ++nt) {
        int j = nt * 16 + rl;
        float cgkj = cgk[j], cbkj = cbk[j], cgvj = cgv[j], cbvj = cbv[j];
        unsigned short vv0[4], vv1[4];
#pragma unroll
        for (int r = 0; r < 4; ++r) {
            int row = w * 16 + h * 4 + r;
            ktile[row * 72 + j] = f2bf(ir0[r] * (k0a[nt][r] - mr0[r] * cgkj) + cbkj);
            ktile[(64 + row) * 72 + j] = f2bf(ir1[r] * (k1a[nt][r] - mr1[r] * cgkj) + cbkj);
            vv0[r] = f2bf(ir0[r] * (v0a[nt][r] - mr0[r] * cgvj) + cbvj);
            vv1[r] = f2bf(ir1[r] * (v1a[nt][r] - mr1[r] * cgvj) + cbvj);
        }
        uint2 p0 = make_uint2((unsigned int)vv0[0] | ((unsigned int)vv0[1] << 16),
                              (unsigned int)vv0[2] | ((unsigned int)vv0[3] << 16));
        uint2 p1 = make_uint2((unsigned int)vv1[0] | ((unsigned int)vv1[1] << 16),
                              (unsigned int)vv1[2] | ((unsigned int)vv1[3] << 16));
        *(uint2*)(&vtile[j * 136 + w * 16 + h * 4]) = p0;
        *(uint2*)(&vtile[j * 136 + 64 + w * 16 + h * 4]) = p1;
    }
    __syncthreads();
#pragma unroll
    for (int i = 0; i < 4; ++i) {
        int flat = (i * 256 + t) * 8;
        int row = flat >> 6, col = flat & 63;
        uint4 kd = *(const uint4*)(&ktile[row * 72 + col]);
        *(uint4*)(kout + (base + row) * 64 + col) = kd;
        int dd = flat >> 7, noff = flat & 127;
        uint4 vd = *(const uint4*)(&vtile[dd * 136 + noff]);
        *(uint4*)(vT + ((long)(bb * 64 + dd)) * NN + nblk + noff) = vd;
    }
    // ---- tail: slots init + LN_s + q + zero U/Z (blocks 0..447) ----
    if (blockIdx.x < 448) {
        int bs = blockIdx.x;
        __syncthreads();
        float* sn = (float*)ktile;
        if (t < 64) {
            float xv = mu[t] + __expf(lsig[t]) * noise[bs * 64 + t];
            slots[bs * 64 + t] = xv;
            float s1 = xv, s2 = xv * xv;
#pragma unroll
            for (int off = 1; off < 64; off <<= 1) {
                s1 += __shfl_xor(s1, off);
                s2 += __shfl_xor(s2, off);
            }
            float m = s1 * (1.f / 64.f);
            float inv = rsqrtf(s2 * (1.f / 64.f) - m * m + LN_EPS);
            sn[t] = (xv - m) * inv * lsg[t] + lsb[t];
            U[bs * 64 + t] = 0.f;
            if (t == 0) Z[bs] = 0.f;
        }
        __syncthreads();
        if (t < 64) {
            float acc = 0.f;
#pragma unroll 8
            for (int i = 0; i < 64; ++i) acc += sn[i] * Wq[i * 64 + t];
            q[bs * 64 + t] = acc * 0.125f;
        }
    }
}

// ---------------- attn: single load volley, then MFMA logits + MFMA PV ----------------
__global__ __launch_bounds__(256) void attn_kernel(
        const unsigned short* __restrict__ kp, const unsigned short* __restrict__ vtp,
        const float* __restrict__ q, float* __restrict__ U, float* __restrict__ Z) {
    __shared__ __align__(16) char smemraw[38912];
    unsigned short* vtile = (unsigned short*)smemraw;          // [64][264] bf16
    unsigned int* plds = (unsigned int*)(smemraw + 33792);     // [4][320]
    int t = threadIdx.x;
    int b = blockIdx.x >> 4, blk = blockIdx.x & 15;
    int w = t >> 6, lane = t & 63;
    int h = lane >> 4, c = lane & 15;
    long rb0 = (long)b * NN + blk * 256 + w * 16;
    // ======== load volley: all k-frags, vT staging, q — one latency exposure ========
    bf16x8 kf[4][2];
#pragma unroll
    for (int i = 0; i < 4; ++i) {
        const unsigned short* ka = kp + (rb0 + i * 64 + c) * 64 + h * 8;
        kf[i][0] = *(const bf16x8*)(ka);
        kf[i][1] = *(const bf16x8*)(ka + 32);
    }
#pragma unroll
    for (int i = 0; i < 8; ++i) {
        int flat = (i * 256 + t) * 8;
        int dd = flat >> 8, noff = flat & 255;
        uint4 vv = *(const uint4*)(vtp + ((long)(b * 64 + dd)) * NN + blk * 256 + noff);
        *(uint4*)(&vtile[dd * 264 + noff]) = vv;
    }
    bf16x8 qf0, qf1;
    {
        int cs = (c < 7) ? c : 0;
        const float* qr = q + (b * NS + cs) * 64 + h * 8;
        float4 q0 = *(const float4*)(qr);
        float4 q1 = *(const float4*)(qr + 4);
        float4 q2 = *(const float4*)(qr + 32);
        float4 q3 = *(const float4*)(qr + 36);
        if (c >= 7) {
            q0 = make_float4(0.f, 0.f, 0.f, 0.f); q1 = q0; q2 = q0; q3 = q0;
        }
        qf0 = pack8(q0, q1);
        qf1 = pack8(q2, q3);
    }
    f32x4 pv[4];
#pragma unroll
    for (int i = 0; i < 4; ++i) pv[i] = (f32x4){0.f, 0.f, 0.f, 0.f};
    float zac = 0.f;
    unsigned int* pw = plds + w * 320;
    __syncthreads();
    // ======== compute: regs + LDS only ========
#pragma unroll
    for (int p = 0; p < 2; ++p) {
#pragma unroll
        for (int sh = 0; sh < 2; ++sh) {
            f32x4 lg = (f32x4){0.f, 0.f, 0.f, 0.f};
            lg = __builtin_amdgcn_mfma_f32_16x16x32_bf16(kf[p * 2 + sh][0], qf0, lg, 0, 0, 0);
            lg = __builtin_amdgcn_mfma_f32_16x16x32_bf16(kf[p * 2 + sh][1], qf1, lg, 0, 0, 0);
            float av[4];
#pragma unroll
            for (int j = 0; j < 4; ++j) {
                float vl = (c < 7) ? lg[j] : -1e30f;
                float mx = vl;
                mx = fmaxf(mx, __shfl_xor(mx, 1));
                mx = fmaxf(mx, __shfl_xor(mx, 2));
                mx = fmaxf(mx, __shfl_xor(mx, 4));
                mx = fmaxf(mx, __shfl_xor(mx, 8));
                float e = (c < 7) ? __expf(lg[j] - mx) : 0.f;
                float se = e;
                se += __shfl_xor(se, 1);
                se += __shfl_xor(se, 2);
                se += __shfl_xor(se, 4);
                se += __shfl_xor(se, 8);
                float a = (c < 7) ? (__fdividef(e, se) + EPS_ATTN) : 0.f;
                av[j] = a;
                zac += a;
            }
            unsigned int w0 = (unsigned int)f2bf(av[0]) | ((unsigned int)f2bf(av[1]) << 16);
            unsigned int w1 = (unsigned int)f2bf(av[2]) | ((unsigned int)f2bf(av[3]) << 16);
            pw[c * 20 + sh * 8 + 2 * h]     = w0;
            pw[c * 20 + sh * 8 + 2 * h + 1] = w1;
        }
        // PV: A = P^T (rows=slots), B = V from LDS vT tile (intra-wave, no barrier)
        u32x4 pr = *(u32x4*)(&pw[c * 20 + 4 * h]);
        bf16x8 pa = __builtin_bit_cast(bf16x8, pr);
        int nloc = p * 128 + ((h < 2) ? (w * 16 + 8 * h) : (48 + w * 16 + 8 * h));
#pragma unroll
        for (int tile = 0; tile < 4; ++tile) {
            bf16x8 bv = *(const bf16x8*)(&vtile[(tile * 16 + c) * 264 + nloc]);
            pv[tile] = __builtin_amdgcn_mfma_f32_16x16x32_bf16(pa, bv, pv[tile], 0, 0, 0);
        }
    }
    // Z reduce
    zac += __shfl_xor(zac, 16);
    zac += __shfl_xor(zac, 32);
    if (h == 0 && c < 7) atomicAdd(Z + b * NS + c, zac);
    __syncthreads();   // before aliasing vtile as ured
    float* ured = (float*)smemraw;   // [4][512]
    if (h < 2) {
#pragma unroll
        for (int tile = 0; tile < 4; ++tile) {
#pragma unroll
            for (int j = 0; j < 4; ++j) {
                ured[w * 512 + (4 * h + j) * 64 + tile * 16 + c] = pv[tile][j];
            }
        }
    }
    __syncthreads();
    for (int idx = t; idx < NS * 64; idx += 256) {
        float tot = ured[idx] + ured[512 + idx] + ured[1024 + idx] + ured[1536 + idx];
        atomicAdd(&U[b * (NS * 64) + idx], tot);
    }
}

// ---------------- slots_post: updates=U/Z, GRU, LN, MLP, next-iter q, zero U/Z ----------------
__global__ __launch_bounds__(256) void slots_post_kernel(
        float* __restrict__ slots, float* __restrict__ U, float* __restrict__ Z,
        const float* __restrict__ gW, const float* __restrict__ gU, const float* __restrict__ gb,
        const float* __restrict__ lmg, const float* __restrict__ lmb,
        const float* __restrict__ W1, const float* __restrict__ b1,
        const float* __restrict__ W2, const float* __restrict__ b2,
        const float* __restrict__ Wq, const float* __restrict__ lsg, const float* __restrict__ lsb,
        float* __restrict__ q, float* __restrict__ outp, int last) {
    __shared__ float up[64], hp[64], mx[192], mh[192], mm[64], hl[128], sn[64];
    int bs = blockIdx.x, t = threadIdx.x;
    if (t < 64) {
        float zsum = Z[bs];
        up[t] = U[bs * 64 + t] / zsum;
        hp[t] = slots[bs * 64 + t];
        U[bs * 64 + t] = 0.f;
        if (t == 0) Z[bs] = 0.f;
    }
    __syncthreads();
    if (t < 192) {
        float xa0 = gb[t], ha0 = gb[192 + t], xa1 = 0.f, ha1 = 0.f;
#pragma unroll 8
        for (int i = 0; i < 64; i += 2) {
            xa0 += up[i] * gW[i * 192 + t];
            ha0 += hp[i] * gU[i * 192 + t];
            xa1 += up[i + 1] * gW[(i + 1) * 192 + t];
            ha1 += hp[i + 1] * gU[(i + 1) * 192 + t];
        }
        mx[t] = xa0 + xa1; mh[t] = ha0 + ha1;
    }
    __syncthreads();
    float hnew = 0.f;
    if (t < 64) {
        float z = 1.f / (1.f + __expf(-(mx[t] + mh[t])));
        float r = 1.f / (1.f + __expf(-(mx[64 + t] + mh[64 + t])));
        float pre = mx[128 + t] + r * mh[128 + t];
        pre = fminf(fmaxf(pre, -15.f), 15.f);
        float e2 = __expf(2.f * pre);
        float hc = (e2 - 1.f) / (e2 + 1.f);
        hnew = z * hp[t] + (1.f - z) * hc;
        float s1 = hnew, s2 = hnew * hnew;
#pragma unroll
        for (int off = 1; off < 64; off <<= 1) { s1 += __shfl_xor(s1, off); s2 += __shfl_xor(s2, off); }
        float m = s1 * (1.f / 64.f);
        float inv = rsqrtf(s2 * (1.f / 64.f) - m * m + LN_EPS);
        mm[t] = (hnew - m) * inv * lmg[t] + lmb[t];
    }
    __syncthreads();
    if (t < 128) {
        float h1 = b1[t], h2 = 0.f;
#pragma unroll 8
        for (int i = 0; i < 64; i += 2) {
            h1 += mm[i] * W1[i * 128 + t];
            h2 += mm[i + 1] * W1[(i + 1) * 128 + t];
        }
        hl[t] = fmaxf(h1 + h2, 0.f);
    }
    __syncthreads();
    if (t < 64) {
        float o = hnew + b2[t], o1 = 0.f;
#pragma unroll 8
        for (int j = 0; j < 128; j += 2) {
            o += hl[j] * W2[j * 64 + t];
            o1 += hl[j + 1] * W2[(j + 1) * 64 + t];
        }
        o += o1;
        slots[bs * 64 + t] = o;
        if (last) outp[bs * 64 + t] = o;
        float s1 = o, s2 = o * o;
#pragma unroll
        for (int off = 1; off < 64; off <<= 1) { s1 += __shfl_xor(s1, off); s2 += __shfl_xor(s2, off); }
        float m = s1 * (1.f / 64.f);
        float inv = rsqrtf(s2 * (1.f / 64.f) - m * m + LN_EPS);
        sn[t] = (o - m) * inv * lsg[t] + lsb[t];
    }
    __syncthreads();
    if (t < 64) {
        float acc = 0.f;
#pragma unroll 8
        for (int i = 0; i < 64; ++i) acc += sn[i] * Wq[i * 64 + t];
        q[bs * 64 + t] = acc * 0.125f;
    }
}

extern "C" void kernel_launch(void* const* d_in, const int* in_sizes, int n_in,
                              void* d_out, int out_size, void* d_ws, size_t ws_size,
                              hipStream_t stream) {
    const float* inputs  = (const float*)d_in[0];
    const float* noise   = (const float*)d_in[1];
    const float* ln_in_g = (const float*)d_in[2];
    const float* ln_in_b = (const float*)d_in[3];
    const float* ln_s_g  = (const float*)d_in[4];
    const float* ln_s_b  = (const float*)d_in[5];
    const float* ln_m_g  = (const float*)d_in[6];
    const float* ln_m_b  = (const float*)d_in[7];
    const float* Wq      = (const float*)d_in[8];
    const float* Wk      = (const float*)d_in[9];
    const float* Wv      = (const float*)d_in[10];
    const float* mu      = (const float*)d_in[11];
    const float* lsig    = (const float*)d_in[12];
    const float* gW      = (const float*)d_in[13];
    const float* gU      = (const float*)d_in[14];
    const float* gb      = (const float*)d_in[15];
    const float* W1      = (const float*)d_in[16];
    const float* b1      = (const float*)d_in[17];
    const float* W2      = (const float*)d_in[18];
    const float* b2      = (const float*)d_in[19];

    char* ws = (char*)d_ws;
    unsigned short* kbuf  = (unsigned short*)ws;                       // 32MB, [b*4096+n][64]
    unsigned short* vtbuf = (unsigned short*)(ws + 33554432);          // 32MB, [b][64][4096]
    float* slots = (float*)(ws + 67108864);
    float* qbuf  = (float*)(ws + 67108864 + 114688);
    float* Ubuf  = (float*)(ws + 67108864 + 2 * 114688);
    float* Zbuf  = (float*)(ws + 67108864 + 3 * 114688);
    unsigned short* GkT = (unsigned short*)(ws + 67108864 + 3 * 114688 + 4096);
    unsigned short* GvT = GkT + 4096;
    float* cgk = (float*)(GvT + 4096);
    float* cbk = cgk + 64;
    float* cgv = cbk + 64;
    float* cbv = cgv + 64;
    float* outp = (float*)d_out;

    prep_kernel<<<128, 64, 0, stream>>>(Wk, Wv, ln_in_g, ln_in_b, GkT, GvT, cgk, cbk, cgv, cbv);
    proj_kernel<<<2048, 256, 0, stream>>>(inputs, GkT, GvT, cgk, cbk, cgv, cbv, kbuf, vtbuf,
                                          noise, mu, lsig, Wq, ln_s_g, ln_s_b,
                                          slots, qbuf, Ubuf, Zbuf);
    for (int it = 0; it < 3; ++it) {
        attn_kernel<<<1024, 256, 0, stream>>>(kbuf, vtbuf, qbuf, Ubuf, Zbuf);
        slots_post_kernel<<<448, 256, 0, stream>>>(slots, Ubuf, Zbuf, gW, gU, gb,
                                                   ln_m_g, ln_m_b, W1, b1, W2, b2,
                                                   Wq, ln_s_g, ln_s_b, qbuf,
                                                   outp, (it == 2) ? 1 : 0);
    }
}